// Round 12
// baseline (374.939 us; speedup 1.0000x reference)
//
#include <hip/hip_runtime.h>
#include <cstdint>

// SpacetimeNonLocalBlock: B=4, C=256, T*H*W=N=6272, IC=128.
// R19: occupancy tiers are POWER-OF-2 (m69: waves/SIMD halve at total-reg
// 64/128/256; no 3-wave tier). flash at 84V+64A=148 regs was hard-capped at
// 2 waves/SIMD all along (explains R17 null, flash11 15.9%). Fix: gload_lds
// staging (frees 16 stg VGPRs; per-lane pre-swizzled SOURCES carry the
// proven K-xor + V-granule LDS images; dest linear) + launch_bounds(256,4)
// -> arch VGPR <=64, total <=128 -> 4 waves/SIMD, 4 blocks/CU (LDS 128KB).
// KS=7 grid (5.36 blocks/CU) can fill the tier (R9's KS=4 grid could not -
// that's why gload_lds "lost" then). R18 V-granule swizzle kept (conflict
// profile proven), mz 64-n split kept, proj/wconv keepers.

#define BB   4
#define CCH  256
#define NPOS 6272
#define ICH  128
#define BNIC ((size_t)BB * NPOS * ICH)
#define TKF  32
#define SLACK 12.0f

typedef __attribute__((ext_vector_type(8)))  _Float16 h8v;  // 8 f16 MFMA frag
typedef __attribute__((ext_vector_type(16))) float fx16;    // 32x32 acc

__device__ __forceinline__ unsigned short f2h(float f) {
  _Float16 h = (_Float16)f;
  return __builtin_bit_cast(unsigned short, h);
}
__device__ __forceinline__ unsigned int pkh(float lo, float hi) {
  return __builtin_bit_cast(unsigned int, __builtin_amdgcn_cvt_pkrtz(lo, hi));
}
__device__ __forceinline__ float h2f(unsigned short u) {
  return (float)__builtin_bit_cast(_Float16, u);
}
// V granule offset (ushorts): row dr, logical 8-ushort chunk c -> swizzled.
__device__ __forceinline__ int vgoff(int dr, int c) {
  return (dr * 4 + (c ^ ((dr >> 1) & 3))) * 8;
}

// ---------------------------------------------------------------------------
// wconv: [Wtheta;Wphi;Wg] (3x128x256 f32) -> Whi/Wlo f16 split. grid 96.
// ---------------------------------------------------------------------------
__global__ __launch_bounds__(256, 1)
void wconv(const float* __restrict__ Wtheta, const float* __restrict__ Wphi,
           const float* __restrict__ Wg,
           unsigned short* __restrict__ Whi, unsigned short* __restrict__ Wlo) {
  const int idx4 = (blockIdx.x * 256 + threadIdx.x) * 4;   // [0, 98304) step 4
  const int p = idx4 >> 15;                                // 0,1,2 (128*256=32768)
  const float* W = (p == 0) ? Wtheta : (p == 1) ? Wphi : Wg;
  const float4 v = *(const float4*)&W[idx4 - (p << 15)];
  const float vv[4] = {v.x, v.y, v.z, v.w};
  ushort4 h, l;
  unsigned short* hp = (unsigned short*)&h;
  unsigned short* lp = (unsigned short*)&l;
  #pragma unroll
  for (int q = 0; q < 4; ++q) {
    _Float16 hh = (_Float16)vv[q];
    hp[q] = __builtin_bit_cast(unsigned short, hh);
    lp[q] = f2h(vv[q] - (float)hh);
  }
  *(ushort4*)&Whi[idx4] = h;
  *(ushort4*)&Wlo[idx4] = l;
}

// ---------------------------------------------------------------------------
// proj_mfma (R15 keeper): grid (N/32, B), 256 thr. c-step 32 per epoch,
// x staged f16 hi/lo [32n][40c-stride] (b128 reads conflict-free).
// ---------------------------------------------------------------------------
__global__ __launch_bounds__(256, 2)
void proj_mfma(const float* __restrict__ x,
               const unsigned short* __restrict__ Whi,
               const unsigned short* __restrict__ Wlo,
               unsigned short* __restrict__ Qg,
               unsigned short* __restrict__ Kg,
               unsigned short* __restrict__ Vtg) {
  __shared__ unsigned short Xhi[32][40];
  __shared__ unsigned short Xlo[32][40];
  const int n0 = blockIdx.x * 32;
  const int b  = blockIdx.y;
  const int tid = threadIdx.x;
  const int lane = tid & 63, wv = tid >> 6;
  const int ln = lane & 31, g = lane >> 5;

  fx16 acc[3];
  acc[0] = (fx16)(0.0f); acc[1] = (fx16)(0.0f); acc[2] = (fx16)(0.0f);

  const int sn = tid & 31, cq = (tid >> 5) * 4;
  const float* xp = x + ((size_t)b * CCH + cq) * NPOS + n0 + sn;

  float pv[4];
  #pragma unroll
  for (int q = 0; q < 4; ++q) pv[q] = xp[(size_t)q * NPOS];

  for (int c0 = 0; c0 < CCH; c0 += 32) {
    {
      ushort4 h4, l4;
      unsigned short* hp = (unsigned short*)&h4;
      unsigned short* lp = (unsigned short*)&l4;
      #pragma unroll
      for (int q = 0; q < 4; ++q) {
        _Float16 hh = (_Float16)pv[q];
        hp[q] = __builtin_bit_cast(unsigned short, hh);
        lp[q] = f2h(pv[q] - (float)hh);
      }
      *(ushort4*)&Xhi[sn][cq] = h4;
      *(ushort4*)&Xlo[sn][cq] = l4;
    }
    if (c0 + 32 < CCH) {
      #pragma unroll
      for (int q = 0; q < 4; ++q) pv[q] = xp[(size_t)(c0 + 32 + q) * NPOS];
    }
    __syncthreads();
    #pragma unroll
    for (int kc = 0; kc < 2; ++kc) {
      const h8v bxh = *(const h8v*)&Xhi[ln][kc * 16 + g * 8];
      const h8v bxl = *(const h8v*)&Xlo[ln][kc * 16 + g * 8];
      #pragma unroll
      for (int t = 0; t < 3; ++t) {
        const int T = wv * 3 + t;
        const size_t wb = ((size_t)(T * 32 + ln)) * CCH + c0 + kc * 16 + g * 8;
        const h8v ah = *(const h8v*)&Whi[wb];
        const h8v al = *(const h8v*)&Wlo[wb];
        acc[t] = __builtin_amdgcn_mfma_f32_32x32x16_f16(ah, bxh, acc[t], 0, 0, 0);
        acc[t] = __builtin_amdgcn_mfma_f32_32x32x16_f16(ah, bxl, acc[t], 0, 0, 0);
        acc[t] = __builtin_amdgcn_mfma_f32_32x32x16_f16(al, bxh, acc[t], 0, 0, 0);
      }
    }
    __syncthreads();
  }

  const float LOG2E = 1.4426950408889634f;
  const int n = n0 + ln;
  #pragma unroll
  for (int t = 0; t < 3; ++t) {
    const int T = wv * 3 + t;
    const int p = T >> 2;
    const int ot = (T & 3) * 32;
    if (p < 2) {
      unsigned short* Out = (p == 0) ? Qg : Kg;
      const float scl = (p == 0) ? LOG2E : 1.0f;
      #pragma unroll
      for (int q = 0; q < 4; ++q) {
        ushort4 v;
        v.x = f2h(acc[t][4 * q + 0] * scl);
        v.y = f2h(acc[t][4 * q + 1] * scl);
        v.z = f2h(acc[t][4 * q + 2] * scl);
        v.w = f2h(acc[t][4 * q + 3] * scl);
        *(ushort4*)&Out[((size_t)b * NPOS + n) * ICH + ot + 8 * q + 4 * g] = v;
      }
    } else {
      #pragma unroll
      for (int r = 0; r < 16; ++r) {
        const int o = ot + (r & 3) + 8 * (r >> 2) + 4 * g;
        Vtg[((size_t)b * ICH + o) * NPOS + n] = f2h(acc[t][r]);
      }
    }
  }
}

// ---------------------------------------------------------------------------
// flash_t<KS>: flash10 math, gload_lds staging (VGPR diet -> 128-reg tier,
// 4 waves/SIMD). grid (49, KS, B). LDS 32 KB: Ks[2] K-xor img, Vs[2] granule
// img — both carried by pre-swizzled per-lane SOURCE addresses, dest linear.
// ---------------------------------------------------------------------------
template <int KS>
__global__ __launch_bounds__(256, 4)
void flash_t(const unsigned short* __restrict__ Qg,
             const unsigned short* __restrict__ Kg,
             const unsigned short* __restrict__ Vtg,
             unsigned short* __restrict__ Opart,
             float* __restrict__ Mpart,
             float* __restrict__ Lpart) {
  constexpr int KLEN = NPOS / KS;
  constexpr int NIT  = KLEN / TKF;
  __shared__ unsigned short Ks[2][TKF * 128];   // 8 KB per buf
  __shared__ unsigned short Vs[2][128 * 32];    // 8 KB per buf (swizzled)

  const int b   = blockIdx.z;
  const int spl = blockIdx.y;
  const int n0  = blockIdx.x * 128;
  const int kb  = spl * KLEN;
  const int tid = threadIdx.x;
  const int lane = tid & 63, wv = tid >> 6;
  const int qlane = lane & 31, g = lane >> 5;
  const int swz = qlane & 15;

  h8v qf[8];
  {
    const size_t qbase = ((size_t)b * NPOS + n0 + 32 * wv + qlane) * ICH;
    #pragma unroll
    for (int cs = 0; cs < 8; ++cs)
      qf[cs] = *(const h8v*)&Qg[qbase + cs * 16 + g * 8];
  }

  // Per-lane 32-bit source offsets for global_load_lds staging.
  // Wave wv, inst i covers LDS ushorts [(wv*2+i)*512, +512); source is
  // pre-permuted so the linear LDS image carries the swizzled layouts.
  unsigned kOff[2], vOff[2];
  #pragma unroll
  for (int i = 0; i < 2; ++i) {
    const unsigned uoff = (unsigned)(wv * 2 + i) * 512 + (unsigned)lane * 8;
    // K: row-major [32][128], 16B slot s at column (s ^ (row&15)).
    const unsigned krow = uoff >> 7, kslot = (uoff >> 3) & 15;
    const unsigned kgc  = kslot ^ (krow & 15);
    kOff[i] = (unsigned)(b * NPOS + kb + krow) * ICH + kgc * 8;
    // V: granule p = dr*4 + (c ^ ((dr>>1)&3)); p = uoff>>3 ->
    // dr = p>>2, c = (p&3) ^ ((p>>3)&3).
    const unsigned vrow = uoff >> 5;
    const unsigned vgc  = ((uoff >> 3) & 3) ^ ((uoff >> 6) & 3);
    vOff[i] = (unsigned)(b * ICH + vrow) * NPOS + kb + vgc * 8;
  }

  auto STAGE = [&](int bufi) {
    #pragma unroll
    for (int i = 0; i < 2; ++i) {
      __builtin_amdgcn_global_load_lds(
          (const __attribute__((address_space(1))) void*)&Kg[kOff[i]],
          (__attribute__((address_space(3))) void*)&Ks[bufi][(wv * 2 + i) * 512],
          16, 0, 0);
      __builtin_amdgcn_global_load_lds(
          (const __attribute__((address_space(1))) void*)&Vtg[vOff[i]],
          (__attribute__((address_space(3))) void*)&Vs[bufi][(wv * 2 + i) * 512],
          16, 0, 0);
      kOff[i] += TKF * ICH;
      vOff[i] += TKF;
    }
  };

  STAGE(0);          // tile 0 -> buf0
  __syncthreads();   // implicit vmcnt(0): tile 0 landed

  float m_run = -1e30f, m_true = -1e30f, l_run = 0.0f;
  fx16 accO[4];
  #pragma unroll
  for (int mt = 0; mt < 4; ++mt) accO[mt] = (fx16)(0.0f);

  for (int it = 0; it < NIT; ++it) {
    const int cur = it & 1;
    if (it + 1 < NIT) STAGE(cur ^ 1);   // prefetch next tile, lands by barrier

    // ---- S^T = K . Q^T ----
    fx16 accS = (fx16)(0.0f);
    #pragma unroll
    for (int cs = 0; cs < 8; ++cs) {
      const h8v aK = *(const h8v*)&Ks[cur][qlane * 128 + ((2 * cs + g) ^ swz) * 8];
      accS = __builtin_amdgcn_mfma_f32_32x32x16_f16(aK, qf[cs], accS, 0, 0, 0);
    }

    // ---- slack-fold online softmax (log2 domain), tree max ----
    float a0 = fmaxf(accS[0], accS[1]),   a1 = fmaxf(accS[2], accS[3]);
    float a2 = fmaxf(accS[4], accS[5]),   a3 = fmaxf(accS[6], accS[7]);
    float a4 = fmaxf(accS[8], accS[9]),   a5 = fmaxf(accS[10], accS[11]);
    float a6 = fmaxf(accS[12], accS[13]), a7 = fmaxf(accS[14], accS[15]);
    a0 = fmaxf(a0, a1); a2 = fmaxf(a2, a3); a4 = fmaxf(a4, a5); a6 = fmaxf(a6, a7);
    float mx = fmaxf(fmaxf(a0, a2), fmaxf(a4, a6));
    mx = fmaxf(mx, __shfl_xor(mx, 32));
    m_true = fmaxf(m_true, mx);
    const bool fold = __any(mx > m_run + SLACK);
    const float mn = fold ? fmaxf(m_run, mx) : m_run;
    float lsum = 0.0f;
    unsigned int pk[4][2];
    #pragma unroll
    for (int u = 0; u < 4; ++u) {
      const float p0 = exp2f(accS[4 * u + 0] - mn);
      const float p1 = exp2f(accS[4 * u + 1] - mn);
      const float p2 = exp2f(accS[4 * u + 2] - mn);
      const float p3 = exp2f(accS[4 * u + 3] - mn);
      lsum += (p0 + p1) + (p2 + p3);
      pk[u][0] = pkh(p0, p1);
      pk[u][1] = pkh(p2, p3);
    }
    lsum += __shfl_xor(lsum, 32);
    if (fold) {
      const float alpha = exp2f(m_run - mn);
      l_run = l_run * alpha + lsum;
      m_run = mn;
      #pragma unroll
      for (int mt = 0; mt < 4; ++mt)
        #pragma unroll
        for (int r = 0; r < 16; ++r) accO[mt][r] *= alpha;
    } else {
      l_run += lsum;
    }

    // ---- PV: O^T += V^T . P^T ----
    #pragma unroll
    for (int s = 0; s < 2; ++s) {
      const unsigned int s0 = pk[2 * s + (g ^ 1)][0];
      const unsigned int s1 = pk[2 * s + (g ^ 1)][1];
      const unsigned int t0 = __shfl_xor(s0, 32);
      const unsigned int t1 = __shfl_xor(s1, 32);
      union { unsigned int u[4]; h8v v; } bP;
      bP.u[0] = g ? t0 : pk[2 * s][0];
      bP.u[1] = g ? t1 : pk[2 * s][1];
      bP.u[2] = g ? pk[2 * s + 1][0] : t0;
      bP.u[3] = g ? pk[2 * s + 1][1] : t1;
      #pragma unroll
      for (int mt = 0; mt < 4; ++mt) {
        const h8v aV = *(const h8v*)&Vs[cur][vgoff(32 * mt + qlane, 2 * s + g)];
        accO[mt] = __builtin_amdgcn_mfma_f32_32x32x16_f16(aV, bP.v, accO[mt], 0, 0, 0);
      }
    }

    __syncthreads();   // drains prefetch (vmcnt) + all reads of cur done
  }

  // epilogue: renormalize to true max, store f16 partial O + (m,l)
  const float scale = exp2f(m_run - m_true);
  const int ncol = n0 + 32 * wv + qlane;
  const size_t obase = (size_t)(b * KS + spl) * ICH * NPOS;
  #pragma unroll
  for (int mt = 0; mt < 4; ++mt)
    #pragma unroll
    for (int r = 0; r < 16; ++r) {
      const int d = 32 * mt + (r & 3) + 8 * (r >> 2) + 4 * g;
      Opart[obase + (size_t)d * NPOS + ncol] = f2h(accO[mt][r] * scale);
    }
  if (g == 0) {
    Mpart[(size_t)(b * KS + spl) * NPOS + ncol] = m_true;
    Lpart[(size_t)(b * KS + spl) * NPOS + ncol] = l_run * scale;
  }
}

// ---------------------------------------------------------------------------
// mz_t<KS> (R17 keeper): fused merge + zres, MFMA. grid (N/64, 2, B).
// ---------------------------------------------------------------------------
template <int KS>
__global__ __launch_bounds__(256, 2)
void mz_t(const float* __restrict__ x,
          const float* __restrict__ Wz,
          const unsigned short* __restrict__ Opart,
          const float* __restrict__ Mpart,
          const float* __restrict__ Lpart,
          float* __restrict__ out) {
  __shared__ float wgt[64][8];
  __shared__ unsigned short Yh[64][24], Yl[64][24];
  __shared__ unsigned short Wzh[128][24], Wzl[128][24];

  const int n0 = blockIdx.x * 64;
  const int c0 = blockIdx.y * 128;
  const int b  = blockIdx.z;
  const int tid = threadIdx.x;
  const int lane = tid & 63, wv = tid >> 6;
  const int ln = lane & 31, g = lane >> 5;

  if (tid < 64) {
    const int n = n0 + tid;
    float m[KS], l[KS];
    float M0 = -1e30f;
    #pragma unroll
    for (int s = 0; s < KS; ++s) {
      m[s] = Mpart[(size_t)(b * KS + s) * NPOS + n];
      l[s] = Lpart[(size_t)(b * KS + s) * NPOS + n];
      M0 = fmaxf(M0, m[s]);
    }
    float w[KS], lt = 0.0f;
    #pragma unroll
    for (int s = 0; s < KS; ++s) { w[s] = exp2f(m[s] - M0); lt += w[s] * l[s]; }
    const float inv = 1.0f / lt;
    #pragma unroll
    for (int s = 0; s < KS; ++s) wgt[tid][s] = w[s] * inv;
  }
  __syncthreads();

  const int np  = tid & 31;
  const int icg = tid >> 5;
  float wA[KS], wB[KS];
  #pragma unroll
  for (int s = 0; s < KS; ++s) { wA[s] = wgt[2 * np][s]; wB[s] = wgt[2 * np + 1][s]; }
  const int wc = tid >> 1, wh = (tid & 1) * 8;
  const float* Wzrow = Wz + (size_t)(c0 + wc) * ICH + wh;

  fx16 acc[2];
  acc[0] = (fx16)(0.0f); acc[1] = (fx16)(0.0f);

  for (int k0 = 0; k0 < ICH; k0 += 16) {
    {
      const float4 w0 = *(const float4*)&Wzrow[k0];
      const float4 w1 = *(const float4*)&Wzrow[k0 + 4];
      const float wv8[8] = {w0.x, w0.y, w0.z, w0.w, w1.x, w1.y, w1.z, w1.w};
      unsigned int hu[4], lu[4];
      #pragma unroll
      for (int q = 0; q < 4; ++q) {
        _Float16 h0 = (_Float16)wv8[2 * q], h1 = (_Float16)wv8[2 * q + 1];
        hu[q] = (unsigned int)__builtin_bit_cast(unsigned short, h0) |
                ((unsigned int)__builtin_bit_cast(unsigned short, h1) << 16);
        lu[q] = (unsigned int)f2h(wv8[2 * q] - (float)h0) |
                ((unsigned int)f2h(wv8[2 * q + 1] - (float)h1) << 16);
      }
      *(uint4*)&Wzh[wc][wh] = make_uint4(hu[0], hu[1], hu[2], hu[3]);
      *(uint4*)&Wzl[wc][wh] = make_uint4(lu[0], lu[1], lu[2], lu[3]);
    }
    {
      unsigned short h0a[2], h1a[2], l0a[2], l1a[2];
      #pragma unroll
      for (int j = 0; j < 2; ++j) {
        const int ic = k0 + icg * 2 + j;
        float y0 = 0.0f, y1 = 0.0f;
        #pragma unroll
        for (int s = 0; s < KS; ++s) {
          const unsigned int u = *(const unsigned int*)
            &Opart[((size_t)(b * KS + s) * ICH + ic) * NPOS + n0 + 2 * np];
          y0 += wA[s] * h2f((unsigned short)(u & 0xffff));
          y1 += wB[s] * h2f((unsigned short)(u >> 16));
        }
        _Float16 hh0 = (_Float16)y0, hh1 = (_Float16)y1;
        h0a[j] = __builtin_bit_cast(unsigned short, hh0);
        h1a[j] = __builtin_bit_cast(unsigned short, hh1);
        l0a[j] = f2h(y0 - (float)hh0);
        l1a[j] = f2h(y1 - (float)hh1);
      }
      const int kc = icg * 2;
      *(ushort2*)&Yh[2 * np][kc]     = make_ushort2(h0a[0], h0a[1]);
      *(ushort2*)&Yh[2 * np + 1][kc] = make_ushort2(h1a[0], h1a[1]);
      *(ushort2*)&Yl[2 * np][kc]     = make_ushort2(l0a[0], l0a[1]);
      *(ushort2*)&Yl[2 * np + 1][kc] = make_ushort2(l1a[0], l1a[1]);
    }
    __syncthreads();

    const int cr = wv * 32 + ln;
    const h8v Ah = *(const h8v*)&Wzh[cr][g * 8];
    const h8v Al = *(const h8v*)&Wzl[cr][g * 8];
    #pragma unroll
    for (int ni = 0; ni < 2; ++ni) {
      const int nr = ni * 32 + ln;
      const h8v Bh = *(const h8v*)&Yh[nr][g * 8];
      const h8v Bl = *(const h8v*)&Yl[nr][g * 8];
      acc[ni] = __builtin_amdgcn_mfma_f32_32x32x16_f16(Ah, Bh, acc[ni], 0, 0, 0);
      acc[ni] = __builtin_amdgcn_mfma_f32_32x32x16_f16(Ah, Bl, acc[ni], 0, 0, 0);
      acc[ni] = __builtin_amdgcn_mfma_f32_32x32x16_f16(Al, Bh, acc[ni], 0, 0, 0);
    }
    __syncthreads();
  }

  #pragma unroll
  for (int ni = 0; ni < 2; ++ni) {
    const int n = n0 + ni * 32 + ln;
    #pragma unroll
    for (int r = 0; r < 16; ++r) {
      const int c = c0 + wv * 32 + (r & 3) + 8 * (r >> 2) + 4 * g;
      const size_t base = ((size_t)(b * CCH + c)) * NPOS + n;
      out[base] = acc[ni][r] + x[base];
    }
  }
}

// ---------------------------------------------------------------------------
extern "C" void kernel_launch(void* const* d_in, const int* in_sizes, int n_in,
                              void* d_out, int out_size, void* d_ws, size_t ws_size,
                              hipStream_t stream) {
  const float* x      = (const float*)d_in[0];
  const float* Wg     = (const float*)d_in[1];
  const float* Wtheta = (const float*)d_in[2];
  const float* Wphi   = (const float*)d_in[3];
  const float* Wz     = (const float*)d_in[4];
  float* out = (float*)d_out;

  unsigned short* Qg    = (unsigned short*)d_ws;
  unsigned short* Kg    = Qg + BNIC;
  unsigned short* Vtg   = Kg + BNIC;
  unsigned short* Opart = Vtg + BNIC;

  // Whi/Wlo overlay the Opart region (dead until flash writes it).
  unsigned short* Whi = Opart;                           // 3*128*256 ushorts
  unsigned short* Wlo = Whi + 3 * 128 * 256;

  wconv<<<dim3(96), 256, 0, stream>>>(Wtheta, Wphi, Wg, Whi, Wlo);
  proj_mfma<<<dim3(NPOS / 32, BB), 256, 0, stream>>>(x, Whi, Wlo, Qg, Kg, Vtg);

  const size_t need7 = (3 + 7) * BNIC * 2 + (size_t)2 * 7 * BB * NPOS * 4;
  if (ws_size >= need7) {
    constexpr int KS = 7;
    float* Mpart = (float*)(Opart + (size_t)KS * BNIC);
    float* Lpart = Mpart + (size_t)KS * BB * NPOS;
    flash_t<KS><<<dim3(NPOS / 128, KS, BB), 256, 0, stream>>>(Qg, Kg, Vtg, Opart, Mpart, Lpart);
    mz_t<KS><<<dim3(NPOS / 64, CCH / 128, BB), 256, 0, stream>>>(x, Wz, Opart, Mpart, Lpart, out);
  } else {
    constexpr int KS = 4;
    float* Mpart = (float*)(Opart + (size_t)KS * BNIC);
    float* Lpart = Mpart + (size_t)KS * BB * NPOS;
    flash_t<KS><<<dim3(NPOS / 128, KS, BB), 256, 0, stream>>>(Qg, Kg, Vtg, Opart, Mpart, Lpart);
    mz_t<KS><<<dim3(NPOS / 64, CCH / 128, BB), 256, 0, stream>>>(x, Wz, Opart, Mpart, Lpart, out);
  }
}